// Round 9
// baseline (239.565 us; speedup 1.0000x reference)
//
#include <hip/hip_runtime.h>

typedef _Float16 f16;
typedef _Float16 f16x8 __attribute__((ext_vector_type(8)));
typedef float f32x16 __attribute__((ext_vector_type(16)));
typedef unsigned int u32;
typedef unsigned int u32x4 __attribute__((ext_vector_type(4)));

#define THREADS 512
#define MTILE   128
#define NBLK    256

// LDS layout (bytes) — 158,720 (1 block/CU, R6 structure)
#define H1_OFF   0        // 2 bufs × f16[128 rows][512 B], 16B XOR key (r&15)<<4
#define XS_OFF   131072   // 2 bufs × f32[128*3]
#define PART_OFF 134144   // 2 bufs × f32[8 wave][128 row][3]
#define LDS_BYTES 158720

// pack 8 f32 -> 8 f16 (RTZ) with relu folded in as packed-f16 max.
// NO permlane: consumer fragments use the matching k-permutation
// rho(h,j) = 4h + (j&3) + 8*(j>>2).
template <int I0>
static __device__ __forceinline__ u32x4 relu_pack8(const f32x16& h) {
  u32 P = __builtin_bit_cast(u32, __builtin_amdgcn_cvt_pkrtz(h[I0+0], h[I0+1]));
  u32 Q = __builtin_bit_cast(u32, __builtin_amdgcn_cvt_pkrtz(h[I0+2], h[I0+3]));
  u32 R = __builtin_bit_cast(u32, __builtin_amdgcn_cvt_pkrtz(h[I0+4], h[I0+5]));
  u32 S = __builtin_bit_cast(u32, __builtin_amdgcn_cvt_pkrtz(h[I0+6], h[I0+7]));
  asm("v_pk_max_f16 %0, %0, 0" : "+v"(P));
  asm("v_pk_max_f16 %0, %0, 0" : "+v"(Q));
  asm("v_pk_max_f16 %0, %0, 0" : "+v"(R));
  asm("v_pk_max_f16 %0, %0, 0" : "+v"(S));
  u32x4 w; w[0] = P; w[1] = Q; w[2] = R; w[3] = S;
  return w;
}

__global__ __launch_bounds__(THREADS, 1)
void fused_mlp_parity(const float* __restrict__ x,
                      const float* __restrict__ w1,
                      const float* __restrict__ b1,
                      const float* __restrict__ w2,
                      const float* __restrict__ b2,
                      const float* __restrict__ w3,
                      const float* __restrict__ b3,
                      float* __restrict__ out, int Bsz) {
  __shared__ __align__(128) unsigned char lds[LDS_BYTES];
  const int tid  = threadIdx.x;
  const int lane = tid & 63;
  const int wave = tid >> 6;          // 8 waves, each owns 32 h-cols
  const int arow = lane & 31;
  const int half = lane >> 5;

  const int ntiles = Bsz / MTILE;
  const int tpb    = ntiles / NBLK;   // 32 at B=1M
  const int t0     = blockIdx.x * tpb;

  float* xsf   = (float*)(lds + XS_OFF);    // + buf*384 floats
  float* partf = (float*)(lds + PART_OFF);  // + buf*3072 floats

  // ---- prologue: stage xs[0], xs[1] ----
  {
    const float4* xg = (const float4*)x;
    if (tid < 96)                      ((float4*)xsf)[tid]            = xg[(size_t)t0*96 + tid];
    else if (tid >= 128 && tid < 224)  ((float4*)xsf)[96 + tid - 128] = xg[(size_t)(t0+1)*96 + (tid-128)];
  }

  // ---- register-resident operands ----
  const int colbase = wave << 5;
  const int col = colbase + arow;
  // w2A with k-permutation rho: element (h,j) = w2[col][16ks + 4h + (j&3) + 8(j>>2)]
  f16x8 w2A[16];
#pragma unroll
  for (int ks = 0; ks < 16; ++ks) {
    const float* src = w2 + (size_t)col*256 + ks*16 + half*4;
    float4 u0 = *(const float4*)src;        // j=0..3
    float4 u1 = *(const float4*)(src + 8);  // j=4..7
    f16x8 v;
    v[0]=(f16)u0.x; v[1]=(f16)u0.y; v[2]=(f16)u0.z; v[3]=(f16)u0.w;
    v[4]=(f16)u1.x; v[5]=(f16)u1.y; v[6]=(f16)u1.z; v[7]=(f16)u1.w;
    w2A[ks] = v;
  }
  f16x8 w1A = {};
  if (half == 0) {
    w1A[0] = (f16)w1[col*3+0]; w1A[1] = (f16)w1[col*3+1];
    w1A[2] = (f16)w1[col*3+2]; w1A[3] = (f16)b1[col];
  }
  // acc C-init: biasInit[reg] = (f32)(f16)b2[row(reg,half)] — replaces bias-MFMA
  f32x16 biasInit;
#pragma unroll
  for (int reg = 0; reg < 16; ++reg) {
    const int rowin32 = (reg & 3) + 8*(reg >> 2) + 4*half;
    biasInit[reg] = (float)(f16)b2[colbase + rowin32];
  }
  // w3A with the same k-permutation rho
  f16x8 w3A[2];
#pragma unroll
  for (int q = 0; q < 2; ++q) {
    f16x8 v = {};
    if (arow < 3) {
#pragma unroll
      for (int j = 0; j < 8; ++j)
        v[j] = (f16)w3[arow*256 + colbase + q*16 + 4*half + (j&3) + 8*(j>>2)];
    }
    w3A[q] = v;
  }
  const float b3r0 = b3[0], b3r1 = b3[1], b3r2 = b3[2];
  const size_t outL = (size_t)Bsz * 2;
  const u32 rk = ((u32)(arow & 15)) << 4;
  const u32 cb = (u32)half << 4;

  // phase B: h1(tile) via MFMA -> pack (no swap) -> swizzled b128 writes
  auto PHASE_B = [&](int buf) {
    unsigned char* h1b = lds + H1_OFF + (u32)buf*65536;
    const float* xb_src = xsf + (u32)buf*384;
#pragma unroll
    for (int nt = 0; nt < 4; ++nt) {
      const int r = nt*32 + arow;
      f16x8 xb = {};
      if (half == 0) {
        const float* xr = xb_src + r*3;
        xb[0] = (f16)xr[0]; xb[1] = (f16)xr[1]; xb[2] = (f16)xr[2];
        xb[3] = (f16)1.0f;
      }
      f32x16 h = {};
      h = __builtin_amdgcn_mfma_f32_32x32x16_f16(w1A, xb, h, 0,0,0);
      const u32 rowbase = ((u32)r << 9);
      {
        u32x4 w = relu_pack8<0>(h);
        const u32 slot = (u32)((colbase + 0)*2 + half*16);
        *(u32x4*)(h1b + rowbase + (slot ^ rk)) = w;
      }
      {
        u32x4 w = relu_pack8<8>(h);
        const u32 slot = (u32)((colbase + 16)*2 + half*16);
        *(u32x4*)(h1b + rowbase + (slot ^ rk)) = w;
      }
    }
  };

  // phases C+E: layer2 MFMA (C-operand bias init), relu-pack, w3-MFMA, part[buf]
  auto PHASE_CE = [&](int buf) {
    const unsigned char* h1b = lds + H1_OFF + (u32)buf*65536;
#pragma unroll
    for (int ntp = 0; ntp < 2; ++ntp) {
      const u32 row0 = (u32)((ntp*2 + 0)*32 + arow) << 9;
      const u32 row1 = (u32)((ntp*2 + 1)*32 + arow) << 9;
      f32x16 acc0, acc1;
      __builtin_amdgcn_s_setprio(1);
      {
        const u32 coff = cb ^ rk;   // ks = 0
        f16x8 fr0 = *(const f16x8*)(h1b + row0 + coff);
        f16x8 fr1 = *(const f16x8*)(h1b + row1 + coff);
        acc0 = __builtin_amdgcn_mfma_f32_32x32x16_f16(w2A[0], fr0, biasInit, 0,0,0);
        acc1 = __builtin_amdgcn_mfma_f32_32x32x16_f16(w2A[0], fr1, biasInit, 0,0,0);
      }
#pragma unroll
      for (int ks = 1; ks < 16; ++ks) {
        const u32 coff = ((((u32)ks) << 5) + cb) ^ rk;
        f16x8 fr0 = *(const f16x8*)(h1b + row0 + coff);
        f16x8 fr1 = *(const f16x8*)(h1b + row1 + coff);
        acc0 = __builtin_amdgcn_mfma_f32_32x32x16_f16(w2A[ks], fr0, acc0, 0,0,0);
        acc1 = __builtin_amdgcn_mfma_f32_32x32x16_f16(w2A[ks], fr1, acc1, 0,0,0);
      }
      __builtin_amdgcn_s_setprio(0);
#pragma unroll
      for (int p = 0; p < 2; ++p) {
        const f32x16& a = p ? acc1 : acc0;
        const int nt = ntp*2 + p;
        f32x16 a3 = {};
        {
          u32x4 w = relu_pack8<0>(a);
          a3 = __builtin_amdgcn_mfma_f32_32x32x16_f16(w3A[0], __builtin_bit_cast(f16x8, w), a3, 0,0,0);
        }
        {
          u32x4 w = relu_pack8<8>(a);
          a3 = __builtin_amdgcn_mfma_f32_32x32x16_f16(w3A[1], __builtin_bit_cast(f16x8, w), a3, 0,0,0);
        }
        if (half == 0) {
          float* pr = partf + (u32)buf*3072 + (u32)((wave<<7) + nt*32 + arow)*3;
          pr[0] = a3[0]; pr[1] = a3[1]; pr[2] = a3[2];
        }
      }
    }
  };

  // FINAL distributed over all 512 threads: row = tid>>2, channel q = tid&3
  auto FINAL = [&](int pbuf, int tidx) {
    const int row = tid >> 2, q = tid & 3;
    const int qc = (q < 3) ? q : 2;                 // q==3 lanes compute channel 2 (discarded)
    const float* pb = partf + (u32)pbuf*3072;
    float l = (q == 0) ? b3r0 : ((q == 1) ? b3r1 : b3r2);
#pragma unroll
    for (int w8 = 0; w8 < 8; ++w8)
      l += pb[(u32)((w8 << 7) + row)*3 + qc];
    const size_t grow = (size_t)(t0 + tidx)*MTILE + row;
    if (q < 3) out[outL + grow*3 + q] = l;
    const int lbase = lane & 60;
    const float l1v = __shfl(l, lbase + 1);
    const float l2v = __shfl(l, lbase + 2);
    if (q == 0) {
      const float inv1p2e = 1.0f / (1.0f + 2.0f * 1e-5f);
      const float tt0 = (1.0f - 2.0f / (1.0f + __expf(-l)))   * inv1p2e;
      const float tt1 = (1.0f - 2.0f / (1.0f + __expf(-l1v))) * inv1p2e;
      const float tt2 = (1.0f - 2.0f / (1.0f + __expf(-l2v))) * inv1p2e;
      const float pred1 = 0.5f * (1.0f - tt0 * tt1 * tt2);
      float2 ov;
      ov.x = (1.0f - pred1 + 0.001f) * (1.0f / 1.002f);
      ov.y = (pred1 + 0.001f) * (1.0f / 1.002f);
      *(float2*)(out + grow*2) = ov;
    }
  };

  __syncthreads();     // xs[0], xs[1] visible
  PHASE_B(0);
  __syncthreads();     // h1[0] visible

  for (int tl = 0; tl < tpb; ++tl) {
    const int cur = tl & 1, nxt = cur ^ 1;

    PHASE_CE(cur);
    if (tl + 1 < tpb) PHASE_B(nxt);
    if (tl + 2 < tpb && tid >= 416) {
      const int i = tid - 416;   // 0..95: stage x(tl+2) into xs[cur]
      ((float4*)(xsf + (u32)cur*384))[i] =
          ((const float4*)x)[(size_t)(t0 + tl + 2)*96 + i];
    }
    if (tl > 0) FINAL(nxt, tl - 1);
    __syncthreads();
  }

  FINAL((tpb - 1) & 1, tpb - 1);
}

extern "C" void kernel_launch(void* const* d_in, const int* in_sizes, int n_in,
                              void* d_out, int out_size, void* d_ws, size_t ws_size,
                              hipStream_t stream) {
  const float* x  = (const float*)d_in[0];
  const float* w1 = (const float*)d_in[1];
  const float* b1 = (const float*)d_in[2];
  const float* w2 = (const float*)d_in[3];
  const float* b2 = (const float*)d_in[4];
  const float* w3 = (const float*)d_in[5];
  const float* b3 = (const float*)d_in[6];
  float* out = (float*)d_out;
  const int Bsz = in_sizes[0] / 3;

  dim3 grid(NBLK), block(THREADS);
  fused_mlp_parity<<<grid, block, 0, stream>>>(x, w1, b1, w2, b2, w3, b3, out, Bsz);
}

// Round 10
// 238.143 us; speedup vs baseline: 1.0060x; 1.0060x over previous
//
#include <hip/hip_runtime.h>

typedef _Float16 f16;
typedef _Float16 f16x8 __attribute__((ext_vector_type(8)));
typedef float f32x16 __attribute__((ext_vector_type(16)));
typedef unsigned int u32;
typedef unsigned int u32x4 __attribute__((ext_vector_type(4)));

#define THREADS 512
#define MTILE   128
#define NBLK    256

// LDS layout (bytes) — 158,720 (1 block/CU, R6 structure)
#define H1_OFF   0        // 2 bufs × f16[128 rows][512 B], 16B XOR key (r&15)<<4
#define XS_OFF   131072   // 2 bufs × f32[128*3]
#define PART_OFF 134144   // 2 bufs × f32[8 wave][128 row][3]
#define LDS_BYTES 158720

// pack 8 f32 -> 8 f16 (RTZ) with relu folded as packed-f16 max.
// NO permlane: consumer fragments use matching k-permutation
// rho(h,j) = 4h + (j&3) + 8*(j>>2).   (verified round 9: passed, absmax 0.03125)
template <int I0>
static __device__ __forceinline__ u32x4 relu_pack8(const f32x16& h) {
  u32 P = __builtin_bit_cast(u32, __builtin_amdgcn_cvt_pkrtz(h[I0+0], h[I0+1]));
  u32 Q = __builtin_bit_cast(u32, __builtin_amdgcn_cvt_pkrtz(h[I0+2], h[I0+3]));
  u32 R = __builtin_bit_cast(u32, __builtin_amdgcn_cvt_pkrtz(h[I0+4], h[I0+5]));
  u32 S = __builtin_bit_cast(u32, __builtin_amdgcn_cvt_pkrtz(h[I0+6], h[I0+7]));
  asm("v_pk_max_f16 %0, %0, 0" : "+v"(P));
  asm("v_pk_max_f16 %0, %0, 0" : "+v"(Q));
  asm("v_pk_max_f16 %0, %0, 0" : "+v"(R));
  asm("v_pk_max_f16 %0, %0, 0" : "+v"(S));
  u32x4 w; w[0] = P; w[1] = Q; w[2] = R; w[3] = S;
  return w;
}

__global__ __launch_bounds__(THREADS, 1)
void fused_mlp_parity(const float* __restrict__ x,
                      const float* __restrict__ w1,
                      const float* __restrict__ b1,
                      const float* __restrict__ w2,
                      const float* __restrict__ b2,
                      const float* __restrict__ w3,
                      const float* __restrict__ b3,
                      float* __restrict__ out, int Bsz) {
  __shared__ __align__(128) unsigned char lds[LDS_BYTES];
  const int tid  = threadIdx.x;
  const int lane = tid & 63;
  const int wave = tid >> 6;          // 8 waves, each owns 32 h-cols
  const int arow = lane & 31;
  const int half = lane >> 5;

  const int ntiles = Bsz / MTILE;
  const int tpb    = ntiles / NBLK;   // 32 at B=1M
  const int t0     = blockIdx.x * tpb;

  float* xsf   = (float*)(lds + XS_OFF);    // + buf*384 floats
  float* partf = (float*)(lds + PART_OFF);  // + buf*3072 floats

  // ---- prologue: stage xs[0], xs[1] ----
  {
    const float4* xg = (const float4*)x;
    if (tid < 96)                      ((float4*)xsf)[tid]            = xg[(size_t)t0*96 + tid];
    else if (tid >= 128 && tid < 224)  ((float4*)xsf)[96 + tid - 128] = xg[(size_t)(t0+1)*96 + (tid-128)];
  }

  // ---- register-resident operands ----
  const int colbase = wave << 5;
  const int col = colbase + arow;
  // w2A with k-permutation rho: element (h,j) = w2[col][16ks + 4h + (j&3) + 8(j>>2)]
  f16x8 w2A[16];
#pragma unroll
  for (int ks = 0; ks < 16; ++ks) {
    const float* src = w2 + (size_t)col*256 + ks*16 + half*4;
    float4 u0 = *(const float4*)src;        // j=0..3
    float4 u1 = *(const float4*)(src + 8);  // j=4..7
    f16x8 v;
    v[0]=(f16)u0.x; v[1]=(f16)u0.y; v[2]=(f16)u0.z; v[3]=(f16)u0.w;
    v[4]=(f16)u1.x; v[5]=(f16)u1.y; v[6]=(f16)u1.z; v[7]=(f16)u1.w;
    w2A[ks] = v;
  }
  f16x8 w1A = {};
  if (half == 0) {
    w1A[0] = (f16)w1[col*3+0]; w1A[1] = (f16)w1[col*3+1];
    w1A[2] = (f16)w1[col*3+2]; w1A[3] = (f16)b1[col];
  }
  // bias via MFMA init (round-6 proven; 4 MFMA/tile but zero live regs held)
  f16x8 b2A = {};  if (half == 0) b2A[0] = (f16)b2[col];
  f16x8 ones = {}; if (half == 0) ones[0] = (f16)1.0f;
  // w3A with the same k-permutation rho
  f16x8 w3A[2];
#pragma unroll
  for (int q = 0; q < 2; ++q) {
    f16x8 v = {};
    if (arow < 3) {
#pragma unroll
      for (int j = 0; j < 8; ++j)
        v[j] = (f16)w3[arow*256 + colbase + q*16 + 4*half + (j&3) + 8*(j>>2)];
    }
    w3A[q] = v;
  }
  const float b3r0 = b3[0], b3r1 = b3[1], b3r2 = b3[2];
  const size_t outL = (size_t)Bsz * 2;
  const u32 rk = ((u32)(arow & 15)) << 4;
  const u32 cb = (u32)half << 4;

  // phase B: h1(tile) via MFMA -> pack (no swap) -> swizzled b128 writes
  auto PHASE_B = [&](int buf) {
    unsigned char* h1b = lds + H1_OFF + (u32)buf*65536;
    const float* xb_src = xsf + (u32)buf*384;
#pragma unroll
    for (int nt = 0; nt < 4; ++nt) {
      const int r = nt*32 + arow;
      f16x8 xb = {};
      if (half == 0) {
        const float* xr = xb_src + r*3;
        xb[0] = (f16)xr[0]; xb[1] = (f16)xr[1]; xb[2] = (f16)xr[2];
        xb[3] = (f16)1.0f;
      }
      f32x16 h = {};
      h = __builtin_amdgcn_mfma_f32_32x32x16_f16(w1A, xb, h, 0,0,0);
      const u32 rowbase = ((u32)r << 9);
      {
        u32x4 w = relu_pack8<0>(h);
        const u32 slot = (u32)((colbase + 0)*2 + half*16);
        *(u32x4*)(h1b + rowbase + (slot ^ rk)) = w;
      }
      {
        u32x4 w = relu_pack8<8>(h);
        const u32 slot = (u32)((colbase + 16)*2 + half*16);
        *(u32x4*)(h1b + rowbase + (slot ^ rk)) = w;
      }
    }
  };

  // phases C+E: layer2 MFMA (bias-MFMA init), relu-pack, w3-MFMA, part[buf]
  auto PHASE_CE = [&](int buf) {
    const unsigned char* h1b = lds + H1_OFF + (u32)buf*65536;
#pragma unroll
    for (int ntp = 0; ntp < 2; ++ntp) {
      f32x16 acc0, acc1;
      {
        f32x16 z = {};
        acc0 = __builtin_amdgcn_mfma_f32_32x32x16_f16(b2A, ones, z, 0,0,0);
        acc1 = __builtin_amdgcn_mfma_f32_32x32x16_f16(b2A, ones, z, 0,0,0);
      }
      const u32 row0 = (u32)((ntp*2 + 0)*32 + arow) << 9;
      const u32 row1 = (u32)((ntp*2 + 1)*32 + arow) << 9;
#pragma unroll
      for (int ks = 0; ks < 16; ++ks) {
        const u32 coff = ((((u32)ks) << 5) + cb) ^ rk;
        f16x8 fr0 = *(const f16x8*)(h1b + row0 + coff);
        f16x8 fr1 = *(const f16x8*)(h1b + row1 + coff);
        acc0 = __builtin_amdgcn_mfma_f32_32x32x16_f16(w2A[ks], fr0, acc0, 0,0,0);
        acc1 = __builtin_amdgcn_mfma_f32_32x32x16_f16(w2A[ks], fr1, acc1, 0,0,0);
      }
#pragma unroll
      for (int p = 0; p < 2; ++p) {
        const f32x16& a = p ? acc1 : acc0;
        const int nt = ntp*2 + p;
        f32x16 a3 = {};
        {
          u32x4 w = relu_pack8<0>(a);
          a3 = __builtin_amdgcn_mfma_f32_32x32x16_f16(w3A[0], __builtin_bit_cast(f16x8, w), a3, 0,0,0);
        }
        {
          u32x4 w = relu_pack8<8>(a);
          a3 = __builtin_amdgcn_mfma_f32_32x32x16_f16(w3A[1], __builtin_bit_cast(f16x8, w), a3, 0,0,0);
        }
        if (half == 0) {
          float* pr = partf + (u32)buf*3072 + (u32)((wave<<7) + nt*32 + arow)*3;
          pr[0] = a3[0]; pr[1] = a3[1]; pr[2] = a3[2];
        }
      }
    }
  };

  // FINAL distributed over all 512 threads: row = tid>>2, channel q = tid&3
  auto FINAL = [&](int pbuf, int tidx) {
    const int row = tid >> 2, q = tid & 3;
    const int qc = (q < 3) ? q : 2;             // q==3 lanes duplicate channel 2
    const float* pb = partf + (u32)pbuf*3072;
    float l = (q == 0) ? b3r0 : ((q == 1) ? b3r1 : b3r2);
#pragma unroll
    for (int w8 = 0; w8 < 8; ++w8)
      l += pb[(u32)((w8 << 7) + row)*3 + qc];
    const size_t grow = (size_t)(t0 + tidx)*MTILE + row;
    if (q < 3) out[outL + grow*3 + q] = l;
    const int lbase = lane & 60;
    const float l1v = __shfl(l, lbase + 1);
    const float l2v = __shfl(l, lbase + 2);
    if (q == 0) {
      const float inv1p2e = 1.0f / (1.0f + 2.0f * 1e-5f);
      const float tt0 = (1.0f - 2.0f / (1.0f + __expf(-l)))   * inv1p2e;
      const float tt1 = (1.0f - 2.0f / (1.0f + __expf(-l1v))) * inv1p2e;
      const float tt2 = (1.0f - 2.0f / (1.0f + __expf(-l2v))) * inv1p2e;
      const float pred1 = 0.5f * (1.0f - tt0 * tt1 * tt2);
      float2 ov;
      ov.x = (1.0f - pred1 + 0.001f) * (1.0f / 1.002f);
      ov.y = (pred1 + 0.001f) * (1.0f / 1.002f);
      *(float2*)(out + grow*2) = ov;
    }
  };

  __syncthreads();     // xs[0], xs[1] visible
  PHASE_B(0);
  __syncthreads();     // h1[0] visible

  for (int tl = 0; tl < tpb; ++tl) {
    const int cur = tl & 1, nxt = cur ^ 1;

    PHASE_CE(cur);
    if (tl + 1 < tpb) PHASE_B(nxt);
    if (tl + 2 < tpb && tid >= 416) {
      const int i = tid - 416;   // 0..95: stage x(tl+2) into xs[cur]
      ((float4*)(xsf + (u32)cur*384))[i] =
          ((const float4*)x)[(size_t)(t0 + tl + 2)*96 + i];
    }
    if (tl > 0) FINAL(nxt, tl - 1);
    __syncthreads();
  }

  FINAL((tpb - 1) & 1, tpb - 1);
}

extern "C" void kernel_launch(void* const* d_in, const int* in_sizes, int n_in,
                              void* d_out, int out_size, void* d_ws, size_t ws_size,
                              hipStream_t stream) {
  const float* x  = (const float*)d_in[0];
  const float* w1 = (const float*)d_in[1];
  const float* b1 = (const float*)d_in[2];
  const float* w2 = (const float*)d_in[3];
  const float* b2 = (const float*)d_in[4];
  const float* w3 = (const float*)d_in[5];
  const float* b3 = (const float*)d_in[6];
  float* out = (float*)d_out;
  const int Bsz = in_sizes[0] / 3;

  dim3 grid(NBLK), block(THREADS);
  fused_mlp_parity<<<grid, block, 0, stream>>>(x, w1, b1, w2, b2, w3, b3, out, Bsz);
}

// Round 11
// 204.069 us; speedup vs baseline: 1.1739x; 1.1670x over previous
//
#include <hip/hip_runtime.h>

typedef _Float16 f16;
typedef _Float16 f16x8 __attribute__((ext_vector_type(8)));
typedef float f32x16 __attribute__((ext_vector_type(16)));
typedef unsigned int u32;
typedef unsigned int u32x4 __attribute__((ext_vector_type(4)));

#define THREADS 512
#define MTILE   128
#define NBLK    256

// LDS layout (bytes) — 158,720 (1 block/CU, R6 structure)
#define H1_OFF   0        // 2 bufs × f16[128 rows][512 B], 16B XOR key (r&15)<<4
#define XS_OFF   131072   // 2 bufs × f32[128*3]
#define PART_OFF 134144   // 2 bufs × f32[8 wave][128 row][3]
#define LDS_BYTES 158720

// pack 8 f32 -> 8 f16 (RTZ) with relu folded as packed-f16 max.
// NO permlane: consumer fragments use matching k-permutation
// rho(h,j) = 4h + (j&3) + 8*(j>>2).   (verified rounds 9/10: absmax 0.03125)
template <int I0>
static __device__ __forceinline__ u32x4 relu_pack8(const f32x16& h) {
  u32 P = __builtin_bit_cast(u32, __builtin_amdgcn_cvt_pkrtz(h[I0+0], h[I0+1]));
  u32 Q = __builtin_bit_cast(u32, __builtin_amdgcn_cvt_pkrtz(h[I0+2], h[I0+3]));
  u32 R = __builtin_bit_cast(u32, __builtin_amdgcn_cvt_pkrtz(h[I0+4], h[I0+5]));
  u32 S = __builtin_bit_cast(u32, __builtin_amdgcn_cvt_pkrtz(h[I0+6], h[I0+7]));
  asm("v_pk_max_f16 %0, %0, 0" : "+v"(P));
  asm("v_pk_max_f16 %0, %0, 0" : "+v"(Q));
  asm("v_pk_max_f16 %0, %0, 0" : "+v"(R));
  asm("v_pk_max_f16 %0, %0, 0" : "+v"(S));
  u32x4 w; w[0] = P; w[1] = Q; w[2] = R; w[3] = S;
  return w;
}

__global__ __launch_bounds__(THREADS, 1)
void fused_mlp_parity(const float* __restrict__ x,
                      const float* __restrict__ w1,
                      const float* __restrict__ b1,
                      const float* __restrict__ w2,
                      const float* __restrict__ b2,
                      const float* __restrict__ w3,
                      const float* __restrict__ b3,
                      float* __restrict__ out, int Bsz) {
  __shared__ __align__(128) unsigned char lds[LDS_BYTES];
  const int tid  = threadIdx.x;
  const int lane = tid & 63;
  const int wave = tid >> 6;          // 8 waves, each owns 32 h-cols
  const int arow = lane & 31;
  const int half = lane >> 5;

  const int ntiles = Bsz / MTILE;
  const int tpb    = ntiles / NBLK;   // 32 at B=1M
  const int t0     = blockIdx.x * tpb;

  float* xsf   = (float*)(lds + XS_OFF);    // + buf*384 floats
  float* partf = (float*)(lds + PART_OFF);  // + buf*3072 floats

  // ---- prologue: stage xs[0], xs[1] ----
  {
    const float4* xg = (const float4*)x;
    if (tid < 96)                      ((float4*)xsf)[tid]            = xg[(size_t)t0*96 + tid];
    else if (tid >= 128 && tid < 224)  ((float4*)xsf)[96 + tid - 128] = xg[(size_t)(t0+1)*96 + (tid-128)];
  }

  // ---- register-resident operands ----
  const int colbase = wave << 5;
  const int col = colbase + arow;
  // w2A with k-permutation rho: element (h,j) = w2[col][16ks + 4h + (j&3) + 8(j>>2)]
  f16x8 w2A[16];
#pragma unroll
  for (int ks = 0; ks < 16; ++ks) {
    const float* src = w2 + (size_t)col*256 + ks*16 + half*4;
    float4 u0 = *(const float4*)src;        // j=0..3
    float4 u1 = *(const float4*)(src + 8);  // j=4..7
    f16x8 v;
    v[0]=(f16)u0.x; v[1]=(f16)u0.y; v[2]=(f16)u0.z; v[3]=(f16)u0.w;
    v[4]=(f16)u1.x; v[5]=(f16)u1.y; v[6]=(f16)u1.z; v[7]=(f16)u1.w;
    w2A[ks] = v;
  }
  f16x8 w1A = {};
  if (half == 0) {
    w1A[0] = (f16)w1[col*3+0]; w1A[1] = (f16)w1[col*3+1];
    w1A[2] = (f16)w1[col*3+2]; w1A[3] = (f16)b1[col];
  }
  // bias via MFMA init (round-6/10 proven; zero live regs held across loop)
  f16x8 b2A = {};  if (half == 0) b2A[0] = (f16)b2[col];
  f16x8 ones = {}; if (half == 0) ones[0] = (f16)1.0f;
  // w3A with the same k-permutation rho
  f16x8 w3A[2];
#pragma unroll
  for (int q = 0; q < 2; ++q) {
    f16x8 v = {};
    if (arow < 3) {
#pragma unroll
      for (int j = 0; j < 8; ++j)
        v[j] = (f16)w3[arow*256 + colbase + q*16 + 4*half + (j&3) + 8*(j>>2)];
    }
    w3A[q] = v;
  }
  const float b3r0 = b3[0], b3r1 = b3[1], b3r2 = b3[2];
  const size_t outL = (size_t)Bsz * 2;
  const u32 rk = ((u32)(arow & 15)) << 4;
  const u32 cb = (u32)half << 4;

  // phase B: h1(tile) via MFMA -> pack (no swap) -> swizzled b128 writes
  auto PHASE_B = [&](int buf) {
    unsigned char* h1b = lds + H1_OFF + (u32)buf*65536;
    const float* xb_src = xsf + (u32)buf*384;
#pragma unroll
    for (int nt = 0; nt < 4; ++nt) {
      const int r = nt*32 + arow;
      f16x8 xb = {};
      if (half == 0) {
        const float* xr = xb_src + r*3;
        xb[0] = (f16)xr[0]; xb[1] = (f16)xr[1]; xb[2] = (f16)xr[2];
        xb[3] = (f16)1.0f;
      }
      f32x16 h = {};
      h = __builtin_amdgcn_mfma_f32_32x32x16_f16(w1A, xb, h, 0,0,0);
      const u32 rowbase = ((u32)r << 9);
      {
        u32x4 w = relu_pack8<0>(h);
        const u32 slot = (u32)((colbase + 0)*2 + half*16);
        *(u32x4*)(h1b + rowbase + (slot ^ rk)) = w;
      }
      {
        u32x4 w = relu_pack8<8>(h);
        const u32 slot = (u32)((colbase + 16)*2 + half*16);
        *(u32x4*)(h1b + rowbase + (slot ^ rk)) = w;
      }
    }
  };

  // phases C+E: layer2 MFMA (bias-MFMA init), relu-pack, w3-MFMA, part[buf]
  auto PHASE_CE = [&](int buf) {
    const unsigned char* h1b = lds + H1_OFF + (u32)buf*65536;
#pragma unroll
    for (int ntp = 0; ntp < 2; ++ntp) {
      f32x16 acc0, acc1;
      {
        f32x16 z = {};
        acc0 = __builtin_amdgcn_mfma_f32_32x32x16_f16(b2A, ones, z, 0,0,0);
        acc1 = __builtin_amdgcn_mfma_f32_32x32x16_f16(b2A, ones, z, 0,0,0);
      }
      const u32 row0 = (u32)((ntp*2 + 0)*32 + arow) << 9;
      const u32 row1 = (u32)((ntp*2 + 1)*32 + arow) << 9;
#pragma unroll
      for (int ks = 0; ks < 16; ++ks) {
        const u32 coff = ((((u32)ks) << 5) + cb) ^ rk;
        f16x8 fr0 = *(const f16x8*)(h1b + row0 + coff);
        f16x8 fr1 = *(const f16x8*)(h1b + row1 + coff);
        acc0 = __builtin_amdgcn_mfma_f32_32x32x16_f16(w2A[ks], fr0, acc0, 0,0,0);
        acc1 = __builtin_amdgcn_mfma_f32_32x32x16_f16(w2A[ks], fr1, acc1, 0,0,0);
      }
#pragma unroll
      for (int p = 0; p < 2; ++p) {
        const f32x16& a = p ? acc1 : acc0;
        const int nt = ntp*2 + p;
        f32x16 a3 = {};
        {
          u32x4 w = relu_pack8<0>(a);
          a3 = __builtin_amdgcn_mfma_f32_32x32x16_f16(w3A[0], __builtin_bit_cast(f16x8, w), a3, 0,0,0);
        }
        {
          u32x4 w = relu_pack8<8>(a);
          a3 = __builtin_amdgcn_mfma_f32_32x32x16_f16(w3A[1], __builtin_bit_cast(f16x8, w), a3, 0,0,0);
        }
        if (half == 0) {
          float* pr = partf + (u32)buf*3072 + (u32)((wave<<7) + nt*32 + arow)*3;
          pr[0] = a3[0]; pr[1] = a3[1]; pr[2] = a3[2];
        }
      }
    }
  };

  // FINAL (round-6 form): waves 0-1 only, coalesced full-line stores
  auto FINAL = [&](int pbuf, int tidx) {
    if (tid < MTILE) {
      const int r = tid;
      const float* pb = partf + (u32)pbuf*3072;
      float l0 = b3r0, l1 = b3r1, l2 = b3r2;
#pragma unroll
      for (int w8 = 0; w8 < 8; ++w8) {
        const float* pr = pb + (u32)((w8<<7) + r)*3;
        l0 += pr[0]; l1 += pr[1]; l2 += pr[2];
      }
      const float inv1p2e = 1.0f / (1.0f + 2.0f * 1e-5f);
      const float tt0 = (1.0f - 2.0f / (1.0f + __expf(-l0))) * inv1p2e;
      const float tt1 = (1.0f - 2.0f / (1.0f + __expf(-l1))) * inv1p2e;
      const float tt2 = (1.0f - 2.0f / (1.0f + __expf(-l2))) * inv1p2e;
      const float pred1 = 0.5f * (1.0f - tt0 * tt1 * tt2);
      const size_t grow = (size_t)(t0 + tidx)*MTILE + r;
      float2 ov;
      ov.x = (1.0f - pred1 + 0.001f) * (1.0f / 1.002f);
      ov.y = (pred1 + 0.001f) * (1.0f / 1.002f);
      *(float2*)(out + grow*2) = ov;
      out[outL + grow*3 + 0] = l0;
      out[outL + grow*3 + 1] = l1;
      out[outL + grow*3 + 2] = l2;
    }
  };

  __syncthreads();     // xs[0], xs[1] visible
  PHASE_B(0);
  __syncthreads();     // h1[0] visible

  for (int tl = 0; tl < tpb; ++tl) {
    const int cur = tl & 1, nxt = cur ^ 1;

    PHASE_CE(cur);
    if (tl + 1 < tpb) PHASE_B(nxt);
    if (tl + 2 < tpb && tid >= 416) {
      const int i = tid - 416;   // 0..95: stage x(tl+2) into xs[cur]
      ((float4*)(xsf + (u32)cur*384))[i] =
          ((const float4*)x)[(size_t)(t0 + tl + 2)*96 + i];
    }
    if (tl > 0) FINAL(nxt, tl - 1);
    __syncthreads();
  }

  FINAL((tpb - 1) & 1, tpb - 1);
}

extern "C" void kernel_launch(void* const* d_in, const int* in_sizes, int n_in,
                              void* d_out, int out_size, void* d_ws, size_t ws_size,
                              hipStream_t stream) {
  const float* x  = (const float*)d_in[0];
  const float* w1 = (const float*)d_in[1];
  const float* b1 = (const float*)d_in[2];
  const float* w2 = (const float*)d_in[3];
  const float* b2 = (const float*)d_in[4];
  const float* w3 = (const float*)d_in[5];
  const float* b3 = (const float*)d_in[6];
  float* out = (float*)d_out;
  const int Bsz = in_sizes[0] / 3;

  dim3 grid(NBLK), block(THREADS);
  fused_mlp_parity<<<grid, block, 0, stream>>>(x, w1, b1, w2, b2, w3, b3, out, Bsz);
}